// Round 10
// baseline (116.982 us; speedup 1.0000x reference)
//
#include <hip/hip_runtime.h>
#include <hip/hip_bf16.h>

#define VOCAB 200000
#define EDIM  256
#define NTILES 12800            // 204800 rows / 16
#define GRID   512              // persistent blocks, 2 per CU
#define ITERS  25               // NTILES / GRID
#define DEPTH  4                // LDS A-buffer ring (3 tiles in flight)

typedef __attribute__((ext_vector_type(4))) float  f32x4;
typedef __attribute__((ext_vector_type(4))) int    i32x4;
typedef __attribute__((ext_vector_type(8))) __bf16 bf16x8;

typedef const __attribute__((address_space(1))) unsigned int* gas_u32p;
typedef __attribute__((address_space(3))) unsigned int* las_u32p;

__device__ __forceinline__ __bf16 f2bf(float f) {
    unsigned u = __builtin_bit_cast(unsigned, f);
    u += 0x7FFFu + ((u >> 16) & 1u);           // round-to-nearest-even
    unsigned short s = (unsigned short)(u >> 16);
    return __builtin_bit_cast(__bf16, s);
}

// Pack B into MFMA fragment order (verified round 1).
// k = a*16 + b;  B[k][j] = core1[b, j, a], core1 is (16,256,16).
// bpk[(kk*16 + nt)*64 + lane] : lane l elem e = B[kk*32 + (l>>4)*8 + e][nt*16 + (l&15)]
__global__ void pack_b_kernel(const float* __restrict__ core1, bf16x8* __restrict__ bpk) {
    int t    = blockIdx.x * 256 + threadIdx.x;   // 0..8191
    int lane = t & 63;
    int nt   = (t >> 6) & 15;
    int kk   = t >> 10;
    int j     = nt * 16 + (lane & 15);
    int kbase = kk * 32 + ((lane >> 4) * 8);
    bf16x8 v;
#pragma unroll
    for (int e = 0; e < 8; ++e) {
        int k = kbase + e;
        int b = k & 15, a = k >> 4;
        v[e] = f2bf(core1[(b * 256 + j) * 16 + a]);
    }
    bpk[t] = v;
}

// A-gather for k-slab kk of a 16-row tile into LDS buffer abuf (zero VGPR).
// Lane l fetches chunk c = kk*8 + (l>>4)*2 + h of row idx_{l&15}; chunk c =
// floats 4c..4c+3 of the row (k = a*16+b): a = c>>2, b = (c&3)*4 ..+3.
// LDS image: kk*2048 + h*1024 + lane*16 -> compute ds_read_b128 contiguous.
__device__ __forceinline__ void issue_gather(const float* __restrict__ core0, int idx,
                                             int kk, char* abuf, int lane) {
    const int q = lane >> 4;
#pragma unroll
    for (int h = 0; h < 2; ++h) {
        int c = kk * 8 + q * 2 + h;
        const float* src = core0 + ((long)(c >> 2) * VOCAB + idx) * 16 + (c & 3) * 4;
        __builtin_amdgcn_global_load_lds((gas_u32p)src,
                                         (las_u32p)(abuf + kk * 2048 + h * 1024), 16, 0, 0);
    }
}

// 512 persistent blocks (2/CU) x 512 thr (8 waves); 25 tiles of 16 rows x 256
// cols each. B panel in registers (wave owns nt=2w,2w+1). A tiles flow through
// a 4-deep LDS ring filled by zero-VGPR global_load_lds gathers issued 3 tiles
// ahead -> ~96 KB standing read in-flight per CU. Idx values staged in LDS
// (lgkm path) so no compiler auto-vmcnt can collapse the pipeline. Per-iter:
// own-gather drain via counted vmcnt(20) + barrier publishes all waves' data.
__global__ __launch_bounds__(512, 4) void tr_embed_kernel(
        const int* __restrict__ x, const float* __restrict__ core0,
        const bf16x8* __restrict__ bpk, float* __restrict__ out) {
    __shared__ char lds[DEPTH * 16384 + ITERS * 16 * 4];   // 64 KB ring + 1.6 KB idx
    int* const sIdx = (int*)(lds + DEPTH * 16384);
    const int tid  = threadIdx.x;
    const int lane = tid & 63;
    const int wave = tid >> 6;                  // 0..7
    const int r    = lane & 15;
    const int q    = lane >> 4;

    // ---- B panel -> registers: wave w owns nt = 2w, 2w+1 (once per block) ----
    bf16x8 B0[8], B1[8];
#pragma unroll
    for (int kk = 0; kk < 8; ++kk) {
        B0[kk] = bpk[(kk * 16 + 2 * wave)     * 64 + lane];
        B1[kk] = bpk[(kk * 16 + 2 * wave + 1) * 64 + lane];
    }

    const int b0 = blockIdx.x;

    // ---- stage ALL this block's idx values into LDS (off the vmcnt path) ----
    for (int j = tid; j < ITERS * 16; j += 512)
        sIdx[j] = x[(b0 + (j >> 4) * GRID) * 16 + (j & 15)];
    __syncthreads();

    // ---- prologue: gather tiles 0..2 into ring slots 0..2, full drain ----
#pragma unroll
    for (int p = 0; p < 3; ++p)
        issue_gather(core0, sIdx[p * 16 + r], wave, lds + p * 16384, lane);
    asm volatile("s_waitcnt vmcnt(0)" ::: "memory");
    __builtin_amdgcn_s_barrier();

    for (int i = 0; i < ITERS; ++i) {
        const int t = b0 + i * GRID;
        char* cur = lds + (i & 3) * 16384;

        // issue gathers for tile i+3 into ring slot (i+3)&3 (2 insts/wave)
        if (i + 3 < ITERS)
            issue_gather(core0, sIdx[(i + 3) * 16 + r], wave,
                         lds + ((i + 3) & 3) * 16384, lane);
        __builtin_amdgcn_sched_barrier(0);      // pin the gather issue up here

        // ---- compute 16 rows x 32 cols per wave from LDS A + reg B ----
        f32x4 acc0 = {}, acc1 = {};
#pragma unroll
        for (int kk = 0; kk < 8; ++kk) {
            f32x4 lo = *(const f32x4*)(cur + kk * 2048 +        lane * 16);
            f32x4 hi = *(const f32x4*)(cur + kk * 2048 + 1024 + lane * 16);
            int p0, p1, p2, p3;                 // RNE packed f32->bf16
            asm("v_cvt_pk_bf16_f32 %0, %1, %2" : "=v"(p0) : "v"(lo[0]), "v"(lo[1]));
            asm("v_cvt_pk_bf16_f32 %0, %1, %2" : "=v"(p1) : "v"(lo[2]), "v"(lo[3]));
            asm("v_cvt_pk_bf16_f32 %0, %1, %2" : "=v"(p2) : "v"(hi[0]), "v"(hi[1]));
            asm("v_cvt_pk_bf16_f32 %0, %1, %2" : "=v"(p3) : "v"(hi[2]), "v"(hi[3]));
            i32x4 pk = { p0, p1, p2, p3 };
            bf16x8 af = __builtin_bit_cast(bf16x8, pk);
            acc0 = __builtin_amdgcn_mfma_f32_16x16x32_bf16(af, B0[kk], acc0, 0, 0, 0);
            acc1 = __builtin_amdgcn_mfma_f32_16x16x32_bf16(af, B1[kk], acc1, 0, 0, 0);
        }

        // C/D layout: col = lane&15, row = q*4 + e (verified)
        float* ob = out + (long)t * 16 * 256 + (q * 4) * 256 + 2 * wave * 16 + r;
#pragma unroll
        for (int e = 0; e < 4; ++e) {
            ob[e * 256]      = acc0[e];
            ob[e * 256 + 16] = acc1[e];
        }

        // counted drain: own g(i+1) (28 ops behind in steady state, >=23 in
        // tail) retires at vmcnt(20); stores + g(i+2), g(i+3) stay in flight.
        // Barrier then publishes every wave's tile-(i+1) data.
        asm volatile("s_waitcnt vmcnt(20)" ::: "memory");
        __builtin_amdgcn_s_barrier();
    }
}

extern "C" void kernel_launch(void* const* d_in, const int* in_sizes, int n_in,
                              void* d_out, int out_size, void* d_ws, size_t ws_size,
                              hipStream_t stream) {
    const int*   x     = (const int*)d_in[0];
    const float* core0 = (const float*)d_in[1];
    const float* core1 = (const float*)d_in[2];
    float* out = (float*)d_out;
    bf16x8* bpk = (bf16x8*)d_ws;                // 128 KB scratch

    pack_b_kernel<<<32, 256, 0, stream>>>(core1, bpk);
    tr_embed_kernel<<<GRID, 512, 0, stream>>>(x, core0, bpk, out);
}